// Round 3
// baseline (486.120 us; speedup 1.0000x reference)
//
#include <hip/hip_runtime.h>
#include <math.h>

#define AA 48          // A = DIST^2 - 1
#define RR 25          // ROUNDS
#define TT 23          // R - 2 scan steps
#define ND 1176        // A*(A+1)/2
#define NOFF 1128      // ND - A (nondiag count)
#define NT 320         // 5 waves; threads 0..293 own 4 outputs each (294*4 = 1176)
#define NOWN 294

// Native vector type: __builtin_nontemporal_store requires a true vector,
// not HIP's float4 class type.
typedef float vfloat4 __attribute__((ext_vector_type(4)));

// d_ws layout: float4 gtab[1176] @ 0 (18816 B), uint32 pairs[1176] @ 18816 (4704 B)
#define GTAB_BYTES (ND * 16)

__global__ __launch_bounds__(256) void build_tables_kernel(
    const float* __restrict__ emb_diag,  // (1, 48)
    const float* __restrict__ emb_nd,    // (1, 1128, 4)
    float4* __restrict__ gtab,           // [1176] value for prod {12,9,8,6}
    uint32_t* __restrict__ pairs)        // [1176] i | (j<<8)
{
    int p = blockIdx.x * 256 + threadIdx.x;
    if (p >= ND) return;
    if (p < AA) {
        pairs[p] = (uint32_t)(p | (p << 8));
        float s = 1.0f / (1.0f + __expf(-emb_diag[p]));
        gtab[p] = make_float4(0.0f, s, 0.0f, 0.0f);   // diag: prod 9 -> sig_diag
    } else {
        int pp = p - AA;
        // row iy of strict upper triangle: S(iy) = 47*iy - iy*(iy-1)/2
        int iy = (int)((95.0f - sqrtf(9025.0f - 8.0f * (float)pp)) * 0.5f);
        if (iy < 0) iy = 0;
        if (iy > 46) iy = 46;
        while (iy < 46 && (47 * (iy + 1) - ((iy + 1) * iy) / 2) <= pp) ++iy;
        while (iy > 0 && (47 * iy - (iy * (iy - 1)) / 2) > pp) --iy;
        int S  = 47 * iy - (iy * (iy - 1)) / 2;
        int ix = iy + 1 + (pp - S);
        pairs[p] = (uint32_t)(iy | (ix << 8));
        const float* e = emb_nd + pp * 4;
        float f12 = 1.0f / (1.0f + __expf(-e[0]));
        float f9  = f12 / (1.0f + __expf(-e[1]));
        float f8  = f9  / (1.0f + __expf(-e[2]));
        float f6  = f8  / (1.0f + __expf(-e[3]));
        gtab[p] = make_float4(f12, f9, f8, f6);
    }
}

// One batch per block: finer grid granularity (4096 blocks vs 1024) smooths the
// occupancy quantization tail and shortens each stage/rec/store phase so the
// resident blocks' store phases interleave, keeping HBM write duty-cycle high.
__global__ __launch_bounds__(NT) void cnn_embed_kernel(
    const int*      __restrict__ x,      // (B, 25, 48) int32 in {0,1}
    const float4*   __restrict__ gtab,   // [1176]
    const uint32_t* __restrict__ pairs,  // [1176]
    float*          __restrict__ out,    // (B, 23, 1176)
    int B)
{
    __shared__ uint8_t xls[RR * AA];   // staged x bits (1200 B)
    __shared__ uint8_t xxc[TT * AA];   // xx codes in {2,3,4} (1104 B)

    const int tid = threadIdx.x;
    const int b   = blockIdx.x;
    if (b >= B) return;

    // ---- Per-thread table registers: thread owns p = 4*tid .. 4*tid+3 ----
    const bool owner = (tid < NOWN);
    int iidx[4], jidx[4];
    float4 g[4];
    if (owner) {
        uint4 pr = ((const uint4*)pairs)[tid];   // pairs[4*tid .. 4*tid+3]
        iidx[0] = pr.x & 0xFF; jidx[0] = (pr.x >> 8) & 0xFF;
        iidx[1] = pr.y & 0xFF; jidx[1] = (pr.y >> 8) & 0xFF;
        iidx[2] = pr.z & 0xFF; jidx[2] = (pr.z >> 8) & 0xFF;
        iidx[3] = pr.w & 0xFF; jidx[3] = (pr.w >> 8) & 0xFF;
        #pragma unroll
        for (int k = 0; k < 4; ++k) g[k] = gtab[4 * tid + k];
    }

    // ---- Stage x bits as packed bytes: 300 int4 loads, one per thread ----
    {
        const int4* xg = (const int4*)(x + (size_t)b * RR * AA);
        if (tid < (RR * AA) / 4) {               // 300 of 320
            int4 v = xg[tid];
            uint32_t packed = (uint32_t)(v.x & 1) | ((uint32_t)(v.y & 1) << 8) |
                              ((uint32_t)(v.z & 1) << 16) | ((uint32_t)(v.w & 1) << 24);
            *((uint32_t*)&xls[tid * 4]) = packed;
        }
    }
    __syncthreads();

    // ---- Integer recurrence; thread = column j, 48 active (short phase) ----
    if (tid < AA) {
        const int j = tid;
        int st = -1, dt = 1;
        #pragma unroll
        for (int t = 0; t < TT; ++t) {
            int a  = xls[t * AA + j];
            int bv = xls[(t + 1) * AA + j];
            int c  = xls[(t + 2) * AA + j];
            int de = a ^ c;                       // data_err
            int me = de ? 0 : (a ^ bv);           // meas_err
            if (me) dt = -dt;
            st += dt * de;
            st = st < -1 ? -1 : (st > 1 ? 1 : st);
            if (!me) dt = (st == 0) ? dt : -st;   // dt*(1-st^2) - st
            xxc[t * AA + j] = (uint8_t)(st + 3);  // xx in {2,3,4}
        }
    }
    __syncthreads();

    // ---- Output: thread writes float4 at p=4*tid for every t ----
    if (owner) {
        float* ob = out + (size_t)b * TT * ND + tid * 4;
        for (int t = 0; t < TT; ++t) {
            const uint8_t* xr = &xxc[t * AA];
            vfloat4 v;
            #pragma unroll
            for (int k = 0; k < 4; ++k) {
                int prod = (int)xr[iidx[k]] * (int)xr[jidx[k]];  // {4,6,8,9,12,16}
                float r = 0.0f;
                r = (prod == 6)  ? g[k].w : r;
                r = (prod == 8)  ? g[k].z : r;
                r = (prod == 9)  ? g[k].y : r;
                r = (prod == 12) ? g[k].x : r;
                r = (prod == 16) ? 1.0f   : r;
                v[k] = r;
            }
            // Pure streaming output, never re-read: bypass L2 write-allocate.
            __builtin_nontemporal_store(v, (vfloat4*)(ob + (size_t)t * ND));
        }
    }
}

extern "C" void kernel_launch(void* const* d_in, const int* in_sizes, int n_in,
                              void* d_out, int out_size, void* d_ws, size_t ws_size,
                              hipStream_t stream) {
    const int*   x  = (const int*)d_in[0];
    const float* ed = (const float*)d_in[1];
    const float* en = (const float*)d_in[2];
    float* out = (float*)d_out;
    float4*   gtab  = (float4*)d_ws;
    uint32_t* pairs = (uint32_t*)((char*)d_ws + GTAB_BYTES);
    const int B = in_sizes[0] / (RR * AA);   // 4096

    hipLaunchKernelGGL(build_tables_kernel, dim3((ND + 255) / 256), dim3(256), 0, stream,
                       ed, en, gtab, pairs);
    hipLaunchKernelGGL(cnn_embed_kernel, dim3(B), dim3(NT), 0, stream,
                       x, gtab, pairs, out, B);
}

// Round 4
// 475.338 us; speedup vs baseline: 1.0227x; 1.0227x over previous
//
#include <hip/hip_runtime.h>
#include <math.h>

#define AA 48          // A = DIST^2 - 1
#define RR 25          // ROUNDS
#define TT 23          // R - 2 scan steps
#define ND 1176        // A*(A+1)/2
#define NT 320         // 5 waves; threads 0..293 own 4 outputs each (294*4 = 1176)
#define NOWN 294
#define XXB (TT * AA)  // 1104 bytes of xx codes per batch
#define TCH 6          // t-rows per streaming block
#define CHUNKS 4       // ceil(23/6)

// d_ws layout: float4 gtab[1176] @ 0 (18816 B), uint32 pairs[1176] @ 18816 (4704 B),
//              uint8 xx[B][23][48] @ 23520 (4.52 MB) -- used only if ws_size permits.
#define GTAB_BYTES (ND * 16)
#define TABLES_BYTES (GTAB_BYTES + ND * 4)

__global__ __launch_bounds__(256) void build_tables_kernel(
    const float* __restrict__ emb_diag,  // (1, 48)
    const float* __restrict__ emb_nd,    // (1, 1128, 4)
    float4* __restrict__ gtab,           // [1176] value for prod {12,9,8,6}
    uint32_t* __restrict__ pairs)        // [1176] i | (j<<8)
{
    int p = blockIdx.x * 256 + threadIdx.x;
    if (p >= ND) return;
    if (p < AA) {
        pairs[p] = (uint32_t)(p | (p << 8));
        float s = 1.0f / (1.0f + __expf(-emb_diag[p]));
        gtab[p] = make_float4(0.0f, s, 0.0f, 0.0f);   // diag: prod 9 -> sig_diag
    } else {
        int pp = p - AA;
        // row iy of strict upper triangle: S(iy) = 47*iy - iy*(iy-1)/2
        int iy = (int)((95.0f - sqrtf(9025.0f - 8.0f * (float)pp)) * 0.5f);
        if (iy < 0) iy = 0;
        if (iy > 46) iy = 46;
        while (iy < 46 && (47 * (iy + 1) - ((iy + 1) * iy) / 2) <= pp) ++iy;
        while (iy > 0 && (47 * iy - (iy * (iy - 1)) / 2) > pp) --iy;
        int S  = 47 * iy - (iy * (iy - 1)) / 2;
        int ix = iy + 1 + (pp - S);
        pairs[p] = (uint32_t)(iy | (ix << 8));
        const float* e = emb_nd + pp * 4;
        float f12 = 1.0f / (1.0f + __expf(-e[0]));
        float f9  = f12 / (1.0f + __expf(-e[1]));
        float f8  = f9  / (1.0f + __expf(-e[2]));
        float f6  = f8  / (1.0f + __expf(-e[3]));
        gtab[p] = make_float4(f12, f9, f8, f6);
    }
}

// ---- Split path kernel 1: integer recurrence, thread = (b, j) ----
// Reads x (19.6 MB), writes xx codes (4.5 MB). Trivially memory-light.
__global__ __launch_bounds__(256) void rec_kernel(
    const int* __restrict__ x,     // (B, 25, 48)
    uint8_t*   __restrict__ xx,    // (B, 23, 48)
    int B)
{
    int idx = blockIdx.x * 256 + threadIdx.x;
    if (idx >= B * AA) return;
    int b = idx / AA;
    int j = idx - b * AA;
    const int* xb = x + (size_t)b * RR * AA + j;
    uint8_t*   o  = xx + (size_t)b * XXB + j;
    int st = -1, dt = 1;
    int a  = xb[0] & 1;
    int bv = xb[AA] & 1;
    #pragma unroll
    for (int t = 0; t < TT; ++t) {
        int c  = xb[(t + 2) * AA] & 1;
        int de = a ^ c;                       // data_err
        int me = de ? 0 : (a ^ bv);           // meas_err
        if (me) dt = -dt;
        st += dt * de;
        st = st < -1 ? -1 : (st > 1 ? 1 : st);
        if (!me) dt = (st == 0) ? dt : -st;   // dt*(1-st^2) - st
        o[t * AA] = (uint8_t)(st + 3);        // xx in {2,3,4}
        a = bv; bv = c;
    }
}

// ---- Split path kernel 2: pure-streaming embed, block = (b, t-chunk) ----
// Homogeneous tiny blocks: stage <=288 B of xx row codes, gather+select,
// store float4. No recurrence, no heavy phases -- maximally fill-like.
__global__ __launch_bounds__(NT) void embed_stream_kernel(
    const uint8_t*  __restrict__ xx,     // (B, 23, 48)
    const float4*   __restrict__ gtab,   // [1176]
    const uint32_t* __restrict__ pairs,  // [1176]
    float*          __restrict__ out,    // (B, 23, 1176)
    int B)
{
    __shared__ uint8_t row[TCH * AA];    // 288 B
    const int blk = blockIdx.x;
    const int b   = blk >> 2;            // CHUNKS = 4
    const int ch  = blk & 3;
    const int t0  = ch * TCH;
    int nt = TT - t0; if (nt > TCH) nt = TCH;   // 6,6,6,5
    const int tid = threadIdx.x;

    // stage nt*48 bytes (nt*12 dwords) of xx codes
    if (tid < nt * (AA / 4)) {
        const uint32_t* src = (const uint32_t*)(xx + (size_t)b * XXB + t0 * AA);
        ((uint32_t*)row)[tid] = src[tid];
    }

    // per-thread tables (same 23.5 KB for every block -> L1/L2 resident)
    const bool owner = (tid < NOWN);
    int iidx[4], jidx[4];
    float4 g[4];
    if (owner) {
        uint4 pr = ((const uint4*)pairs)[tid];
        iidx[0] = pr.x & 0xFF; jidx[0] = (pr.x >> 8) & 0xFF;
        iidx[1] = pr.y & 0xFF; jidx[1] = (pr.y >> 8) & 0xFF;
        iidx[2] = pr.z & 0xFF; jidx[2] = (pr.z >> 8) & 0xFF;
        iidx[3] = pr.w & 0xFF; jidx[3] = (pr.w >> 8) & 0xFF;
        #pragma unroll
        for (int k = 0; k < 4; ++k) g[k] = gtab[4 * tid + k];
    }
    __syncthreads();

    if (owner) {
        float* ob = out + ((size_t)b * TT + t0) * ND + tid * 4;
        for (int tt = 0; tt < nt; ++tt) {
            const uint8_t* xr = &row[tt * AA];
            float4 v;
            float* vf = (float*)&v;
            #pragma unroll
            for (int k = 0; k < 4; ++k) {
                int prod = (int)xr[iidx[k]] * (int)xr[jidx[k]];  // {4,6,8,9,12,16}
                float r = 0.0f;
                r = (prod == 6)  ? g[k].w : r;
                r = (prod == 8)  ? g[k].z : r;
                r = (prod == 9)  ? g[k].y : r;
                r = (prod == 12) ? g[k].x : r;
                r = (prod == 16) ? 1.0f   : r;
                vf[k] = r;
            }
            *((float4*)(ob + (size_t)tt * ND)) = v;
        }
    }
}

// ---- Fallback: proven monolithic kernel (used if ws too small for xx) ----
__global__ __launch_bounds__(NT) void cnn_embed_kernel(
    const int*      __restrict__ x,      // (B, 25, 48) int32 in {0,1}
    const float4*   __restrict__ gtab,   // [1176]
    const uint32_t* __restrict__ pairs,  // [1176]
    float*          __restrict__ out,    // (B, 23, 1176)
    int B)
{
    __shared__ uint8_t xls[RR * AA];   // staged x bits (1200 B)
    __shared__ uint8_t xxc[TT * AA];   // xx codes in {2,3,4} (1104 B)

    const int tid = threadIdx.x;
    const int b   = blockIdx.x;
    if (b >= B) return;

    const bool owner = (tid < NOWN);
    int iidx[4], jidx[4];
    float4 g[4];
    if (owner) {
        uint4 pr = ((const uint4*)pairs)[tid];
        iidx[0] = pr.x & 0xFF; jidx[0] = (pr.x >> 8) & 0xFF;
        iidx[1] = pr.y & 0xFF; jidx[1] = (pr.y >> 8) & 0xFF;
        iidx[2] = pr.z & 0xFF; jidx[2] = (pr.z >> 8) & 0xFF;
        iidx[3] = pr.w & 0xFF; jidx[3] = (pr.w >> 8) & 0xFF;
        #pragma unroll
        for (int k = 0; k < 4; ++k) g[k] = gtab[4 * tid + k];
    }

    {
        const int4* xg = (const int4*)(x + (size_t)b * RR * AA);
        if (tid < (RR * AA) / 4) {               // 300 of 320
            int4 v = xg[tid];
            uint32_t packed = (uint32_t)(v.x & 1) | ((uint32_t)(v.y & 1) << 8) |
                              ((uint32_t)(v.z & 1) << 16) | ((uint32_t)(v.w & 1) << 24);
            *((uint32_t*)&xls[tid * 4]) = packed;
        }
    }
    __syncthreads();

    if (tid < AA) {
        const int j = tid;
        int st = -1, dt = 1;
        #pragma unroll
        for (int t = 0; t < TT; ++t) {
            int a  = xls[t * AA + j];
            int bv = xls[(t + 1) * AA + j];
            int c  = xls[(t + 2) * AA + j];
            int de = a ^ c;
            int me = de ? 0 : (a ^ bv);
            if (me) dt = -dt;
            st += dt * de;
            st = st < -1 ? -1 : (st > 1 ? 1 : st);
            if (!me) dt = (st == 0) ? dt : -st;
            xxc[t * AA + j] = (uint8_t)(st + 3);
        }
    }
    __syncthreads();

    if (owner) {
        float* ob = out + (size_t)b * TT * ND + tid * 4;
        for (int t = 0; t < TT; ++t) {
            const uint8_t* xr = &xxc[t * AA];
            float4 v;
            float* vf = (float*)&v;
            #pragma unroll
            for (int k = 0; k < 4; ++k) {
                int prod = (int)xr[iidx[k]] * (int)xr[jidx[k]];
                float r = 0.0f;
                r = (prod == 6)  ? g[k].w : r;
                r = (prod == 8)  ? g[k].z : r;
                r = (prod == 9)  ? g[k].y : r;
                r = (prod == 12) ? g[k].x : r;
                r = (prod == 16) ? 1.0f   : r;
                vf[k] = r;
            }
            *((float4*)(ob + (size_t)t * ND)) = v;
        }
    }
}

extern "C" void kernel_launch(void* const* d_in, const int* in_sizes, int n_in,
                              void* d_out, int out_size, void* d_ws, size_t ws_size,
                              hipStream_t stream) {
    const int*   x  = (const int*)d_in[0];
    const float* ed = (const float*)d_in[1];
    const float* en = (const float*)d_in[2];
    float* out = (float*)d_out;
    float4*   gtab  = (float4*)d_ws;
    uint32_t* pairs = (uint32_t*)((char*)d_ws + GTAB_BYTES);
    uint8_t*  xx    = (uint8_t*)((char*)d_ws + TABLES_BYTES);
    const int B = in_sizes[0] / (RR * AA);   // 4096

    hipLaunchKernelGGL(build_tables_kernel, dim3((ND + 255) / 256), dim3(256), 0, stream,
                       ed, en, gtab, pairs);

    const size_t need = (size_t)TABLES_BYTES + (size_t)B * XXB;
    if (ws_size >= need) {
        // Split path: tiny recurrence kernel + pure-streaming embed kernel.
        const int rthreads = B * AA;
        hipLaunchKernelGGL(rec_kernel, dim3((rthreads + 255) / 256), dim3(256), 0, stream,
                           x, xx, B);
        hipLaunchKernelGGL(embed_stream_kernel, dim3(B * CHUNKS), dim3(NT), 0, stream,
                           xx, gtab, pairs, out, B);
    } else {
        hipLaunchKernelGGL(cnn_embed_kernel, dim3(B), dim3(NT), 0, stream,
                           x, gtab, pairs, out, B);
    }
}